// Round 1
// baseline (25333.841 us; speedup 1.0000x reference)
//
#include <hip/hip_runtime.h>

#define DIM 64
#define DIM4 (DIM / 4)

// cur[n] = concat(user_emb, item_emb)[n], float4-vectorized
__global__ void init_concat(const float4* __restrict__ ue, const float4* __restrict__ ie,
                            float4* __restrict__ cur, long nU4, long total4) {
    long i = (long)blockIdx.x * blockDim.x + threadIdx.x;
    if (i >= total4) return;
    cur[i] = (i < nU4) ? ue[i] : ie[i - nU4];
}

// y[dst] += vals * x[src], edge-parallel, 16 lanes per edge, float4 per lane
__global__ void spmm_scatter(const int* __restrict__ src, const int* __restrict__ dst,
                             const float* __restrict__ vals, const float* __restrict__ x,
                             float* __restrict__ y, int E) {
    long gid = (long)blockIdx.x * blockDim.x + threadIdx.x;
    int lane = (int)(gid & 15);
    long e = gid >> 4;
    if (e >= E) return;
    int s = src[e];
    int d = dst[e];
    float v = vals[e];
    float4 r = ((const float4*)(x + (long)s * DIM))[lane];
    float* yp = y + (long)d * DIM + lane * 4;
    atomicAdd(yp + 0, v * r.x);
    atomicAdd(yp + 1, v * r.y);
    atomicAdd(yp + 2, v * r.z);
    atomicAdd(yp + 3, v * r.w);
}

// acc[b] += x[idx[b] + offset], 16 lanes per row
__global__ void gather_accum(const int* __restrict__ idx, int offset,
                             const float* __restrict__ x, float* __restrict__ acc, int B) {
    long gid = (long)blockIdx.x * blockDim.x + threadIdx.x;
    int lane = (int)(gid & 15);
    long b = gid >> 4;
    if (b >= B) return;
    long node = (long)idx[b] + offset;
    float4 r = ((const float4*)(x + node * DIM))[lane];
    float4* a = (float4*)(acc + b * DIM) + lane;
    float4 av = *a;
    av.x += r.x; av.y += r.y; av.z += r.z; av.w += r.w;
    *a = av;
}

// out[b] = dot(accU[b], accI[b]) / 16   (both sides carry the /4 layer-mean)
__global__ void dot_pairs(const float* __restrict__ aU, const float* __restrict__ aI,
                          float* __restrict__ out, int B) {
    long gid = (long)blockIdx.x * blockDim.x + threadIdx.x;
    int lane = (int)(gid & 15);
    long b = gid >> 4;
    if (b >= B) return;
    float4 u = ((const float4*)(aU + b * DIM))[lane];
    float4 v = ((const float4*)(aI + b * DIM))[lane];
    float s = u.x * v.x + u.y * v.y + u.z * v.z + u.w * v.w;
    s += __shfl_xor(s, 1);
    s += __shfl_xor(s, 2);
    s += __shfl_xor(s, 4);
    s += __shfl_xor(s, 8);
    if (lane == 0) out[b] = s * (1.0f / 16.0f);
}

extern "C" void kernel_launch(void* const* d_in, const int* in_sizes, int n_in,
                              void* d_out, int out_size, void* d_ws, size_t ws_size,
                              hipStream_t stream) {
    const int*   users = (const int*)d_in[0];
    const int*   items = (const int*)d_in[1];
    const int*   esrc  = (const int*)d_in[2];
    const int*   edst  = (const int*)d_in[3];
    const float* evals = (const float*)d_in[4];
    const float* uemb  = (const float*)d_in[5];
    const float* iemb  = (const float*)d_in[6];

    const int B  = in_sizes[0];
    const int E  = in_sizes[2];
    const int nU = in_sizes[5] / DIM;
    const int nI = in_sizes[6] / DIM;
    const int N  = nU + nI;

    float* cur  = (float*)d_ws;
    float* nxt  = cur  + (size_t)N * DIM;
    float* accU = nxt  + (size_t)N * DIM;
    float* accI = accU + (size_t)B * DIM;
    float* gout = (float*)d_out;

    const int T = 256;

    // zero the per-target accumulators (accU|accI contiguous)
    hipMemsetAsync(accU, 0, (size_t)B * DIM * 2 * sizeof(float), stream);

    // cur = concat(user_emb, item_emb)
    long total4 = (long)N * DIM4;
    long nU4    = (long)nU * DIM4;
    init_concat<<<(int)((total4 + T - 1) / T), T, 0, stream>>>(
        (const float4*)uemb, (const float4*)iemb, (float4*)cur, nU4, total4);

    // layer-0 term: acc += cur[targets]
    int gb = (int)(((long)B * 16 + T - 1) / T);
    gather_accum<<<gb, T, 0, stream>>>(users, 0,  cur, accU, B);
    gather_accum<<<gb, T, 0, stream>>>(items, nU, cur, accI, B);

    int sb = (int)(((long)E * 16 + T - 1) / T);
    for (int l = 0; l < 3; ++l) {
        hipMemsetAsync(nxt, 0, (size_t)N * DIM * sizeof(float), stream);
        spmm_scatter<<<sb, T, 0, stream>>>(esrc, edst, evals, cur, nxt, E);
        gather_accum<<<gb, T, 0, stream>>>(users, 0,  nxt, accU, B);
        gather_accum<<<gb, T, 0, stream>>>(items, nU, nxt, accI, B);
        float* t = cur; cur = nxt; nxt = t;
    }

    dot_pairs<<<(int)(((long)B * 16 + T - 1) / T), T, 0, stream>>>(accU, accI, gout, B);
}

// Round 2
// 2305.918 us; speedup vs baseline: 10.9864x; 10.9864x over previous
//
#include <hip/hip_runtime.h>

#define DIM 64
#define DIM4 (DIM / 4)

// ---------- shared small kernels ----------

__global__ void init_concat(const float4* __restrict__ ue, const float4* __restrict__ ie,
                            float4* __restrict__ cur, long nU4, long total4) {
    long i = (long)blockIdx.x * blockDim.x + threadIdx.x;
    if (i >= total4) return;
    cur[i] = (i < nU4) ? ue[i] : ie[i - nU4];
}

__global__ void gather_accum(const int* __restrict__ idx, int offset,
                             const float* __restrict__ x, float* __restrict__ acc, int B) {
    long gid = (long)blockIdx.x * blockDim.x + threadIdx.x;
    int lane = (int)(gid & 15);
    long b = gid >> 4;
    if (b >= B) return;
    long node = (long)idx[b] + offset;
    float4 r = ((const float4*)(x + node * DIM))[lane];
    float4* a = (float4*)(acc + b * DIM) + lane;
    float4 av = *a;
    av.x += r.x; av.y += r.y; av.z += r.z; av.w += r.w;
    *a = av;
}

__global__ void dot_pairs(const float* __restrict__ aU, const float* __restrict__ aI,
                          float* __restrict__ out, int B) {
    long gid = (long)blockIdx.x * blockDim.x + threadIdx.x;
    int lane = (int)(gid & 15);
    long b = gid >> 4;
    if (b >= B) return;
    float4 u = ((const float4*)(aU + b * DIM))[lane];
    float4 v = ((const float4*)(aI + b * DIM))[lane];
    float s = u.x * v.x + u.y * v.y + u.z * v.z + u.w * v.w;
    s += __shfl_xor(s, 1);
    s += __shfl_xor(s, 2);
    s += __shfl_xor(s, 4);
    s += __shfl_xor(s, 8);
    if (lane == 0) out[b] = s * (1.0f / 16.0f);
}

// ---------- CSR build ----------

__global__ void count_deg(const int* __restrict__ dst, int* __restrict__ cnt, int E) {
    int e = blockIdx.x * blockDim.x + threadIdx.x;
    if (e >= E) return;
    atomicAdd(&cnt[dst[e]], 1);
}

// per-block inclusive scan; partial results into out (one past: caller passes rowptr+1)
__global__ void scan_block(const int* __restrict__ cnt, int* __restrict__ out,
                           int* __restrict__ blockSums, int n) {
    __shared__ int tmp[256];
    int i = blockIdx.x * 256 + threadIdx.x;
    int v = (i < n) ? cnt[i] : 0;
    tmp[threadIdx.x] = v;
    __syncthreads();
    for (int off = 1; off < 256; off <<= 1) {
        int t = (threadIdx.x >= off) ? tmp[threadIdx.x - off] : 0;
        __syncthreads();
        tmp[threadIdx.x] += t;
        __syncthreads();
    }
    if (i < n) out[i] = tmp[threadIdx.x];
    if (threadIdx.x == 255) blockSums[blockIdx.x] = tmp[255];
}

// single block: exclusive scan of block sums (nb <= 1024)
__global__ void scan_sums(int* __restrict__ blockSums, int nb) {
    __shared__ int tmp[1024];
    int i = threadIdx.x;
    tmp[i] = (i < nb) ? blockSums[i] : 0;
    __syncthreads();
    for (int off = 1; off < 1024; off <<= 1) {
        int t = (i >= off) ? tmp[i - off] : 0;
        __syncthreads();
        tmp[i] += t;
        __syncthreads();
    }
    if (i < nb) blockSums[i] = (i > 0) ? tmp[i - 1] : 0;
}

// rowptr[i+1] += blockOffset;  cursor[i] = rowptr[i+1] - cnt[i];  rowptr[0] = 0
__global__ void scan_finalize(const int* __restrict__ cnt, const int* __restrict__ blockSums,
                              int* __restrict__ rowptr, int* __restrict__ cursor, int n) {
    int i = blockIdx.x * 256 + threadIdx.x;
    if (i >= n) return;
    int inc = rowptr[i + 1] + blockSums[blockIdx.x];
    rowptr[i + 1] = inc;
    cursor[i] = inc - cnt[i];
    if (i == 0) rowptr[0] = 0;
}

__global__ void csr_fill(const int* __restrict__ src, const int* __restrict__ dst,
                         const float* __restrict__ vals, int* __restrict__ cursor,
                         int2* __restrict__ pairs, int E) {
    int e = blockIdx.x * blockDim.x + threadIdx.x;
    if (e >= E) return;
    int d = dst[e];
    int pos = atomicAdd(&cursor[d], 1);
    pairs[pos] = make_int2(src[e], __float_as_int(vals[e]));
}

// ---------- pull-mode SpMM: one 16-lane group per destination row ----------

__global__ void spmm_pull(const int* __restrict__ rowptr, const int2* __restrict__ pairs,
                          const float* __restrict__ x, float* __restrict__ y, int Nrows) {
    long gid = (long)blockIdx.x * blockDim.x + threadIdx.x;
    int lane = (int)(gid & 15);
    long r = gid >> 4;
    if (r >= Nrows) return;
    int beg = rowptr[r];
    int end = rowptr[r + 1];
    float4 acc = make_float4(0.f, 0.f, 0.f, 0.f);
    int e = beg;
    for (; e + 1 < end; e += 2) {
        int2 p0 = pairs[e];
        int2 p1 = pairs[e + 1];
        float v0 = __int_as_float(p0.y);
        float v1 = __int_as_float(p1.y);
        float4 x0 = ((const float4*)(x + (long)p0.x * DIM))[lane];
        float4 x1 = ((const float4*)(x + (long)p1.x * DIM))[lane];
        acc.x += v0 * x0.x; acc.y += v0 * x0.y; acc.z += v0 * x0.z; acc.w += v0 * x0.w;
        acc.x += v1 * x1.x; acc.y += v1 * x1.y; acc.z += v1 * x1.z; acc.w += v1 * x1.w;
    }
    if (e < end) {
        int2 p = pairs[e];
        float v = __int_as_float(p.y);
        float4 xr = ((const float4*)(x + (long)p.x * DIM))[lane];
        acc.x += v * xr.x; acc.y += v * xr.y; acc.z += v * xr.z; acc.w += v * xr.w;
    }
    ((float4*)(y + r * DIM))[lane] = acc;
}

// ---------- fallback (round-1 atomic scatter) ----------

__global__ void spmm_scatter(const int* __restrict__ src, const int* __restrict__ dst,
                             const float* __restrict__ vals, const float* __restrict__ x,
                             float* __restrict__ y, int E) {
    long gid = (long)blockIdx.x * blockDim.x + threadIdx.x;
    int lane = (int)(gid & 15);
    long e = gid >> 4;
    if (e >= E) return;
    int s = src[e];
    int d = dst[e];
    float v = vals[e];
    float4 r = ((const float4*)(x + (long)s * DIM))[lane];
    float* yp = y + (long)d * DIM + lane * 4;
    atomicAdd(yp + 0, v * r.x);
    atomicAdd(yp + 1, v * r.y);
    atomicAdd(yp + 2, v * r.z);
    atomicAdd(yp + 3, v * r.w);
}

extern "C" void kernel_launch(void* const* d_in, const int* in_sizes, int n_in,
                              void* d_out, int out_size, void* d_ws, size_t ws_size,
                              hipStream_t stream) {
    const int*   users = (const int*)d_in[0];
    const int*   items = (const int*)d_in[1];
    const int*   esrc  = (const int*)d_in[2];
    const int*   edst  = (const int*)d_in[3];
    const float* evals = (const float*)d_in[4];
    const float* uemb  = (const float*)d_in[5];
    const float* iemb  = (const float*)d_in[6];

    const int B  = in_sizes[0];
    const int E  = in_sizes[2];
    const int nU = in_sizes[5] / DIM;
    const int nI = in_sizes[6] / DIM;
    const int N  = nU + nI;

    const int T = 256;
    float* gout = (float*)d_out;

    // workspace layout
    size_t need = ((size_t)2 * N * DIM + (size_t)2 * B * DIM) * 4   // cur,nxt,accU,accI
                + (size_t)E * 8                                      // pairs
                + ((size_t)3 * N + 2 + 1024) * 4;                    // cnt,rowptr,cursor,blockSums
    float* cur  = (float*)d_ws;
    float* nxt  = cur  + (size_t)N * DIM;
    float* accU = nxt  + (size_t)N * DIM;
    float* accI = accU + (size_t)B * DIM;
    int2*  pairs = (int2*)(accI + (size_t)B * DIM);
    int*   cnt    = (int*)(pairs + (size_t)E);
    int*   rowptr = cnt + N;
    int*   cursor = rowptr + (N + 1);
    int*   blockSums = cursor + N;

    long total4 = (long)N * DIM4;
    long nU4    = (long)nU * DIM4;
    int gb = (int)(((long)B * 16 + T - 1) / T);
    int eb = (E + T - 1) / T;

    hipMemsetAsync(accU, 0, (size_t)B * DIM * 2 * sizeof(float), stream);
    init_concat<<<(int)((total4 + T - 1) / T), T, 0, stream>>>(
        (const float4*)uemb, (const float4*)iemb, (float4*)cur, nU4, total4);
    gather_accum<<<gb, T, 0, stream>>>(users, 0,  cur, accU, B);
    gather_accum<<<gb, T, 0, stream>>>(items, nU, cur, accI, B);

    if (ws_size >= need) {
        // ---- CSR build (per call; edges are constant but no static state allowed) ----
        hipMemsetAsync(cnt, 0, (size_t)N * sizeof(int), stream);
        count_deg<<<eb, T, 0, stream>>>(edst, cnt, E);
        int nb = (N + 255) / 256;                     // <= 1024 for N <= 262144
        scan_block<<<nb, 256, 0, stream>>>(cnt, rowptr + 1, blockSums, N);
        scan_sums<<<1, 1024, 0, stream>>>(blockSums, nb);
        scan_finalize<<<nb, 256, 0, stream>>>(cnt, blockSums, rowptr, cursor, N);
        csr_fill<<<eb, T, 0, stream>>>(esrc, edst, evals, cursor, pairs, E);

        int pb = (int)(((long)N * 16 + T - 1) / T);
        for (int l = 0; l < 3; ++l) {
            spmm_pull<<<pb, T, 0, stream>>>(rowptr, pairs, cur, nxt, N);
            gather_accum<<<gb, T, 0, stream>>>(users, 0,  nxt, accU, B);
            gather_accum<<<gb, T, 0, stream>>>(items, nU, nxt, accI, B);
            float* t = cur; cur = nxt; nxt = t;
        }
    } else {
        // fallback: atomic scatter path
        int sb = (int)(((long)E * 16 + T - 1) / T);
        for (int l = 0; l < 3; ++l) {
            hipMemsetAsync(nxt, 0, (size_t)N * DIM * sizeof(float), stream);
            spmm_scatter<<<sb, T, 0, stream>>>(esrc, edst, evals, cur, nxt, E);
            gather_accum<<<gb, T, 0, stream>>>(users, 0,  nxt, accU, B);
            gather_accum<<<gb, T, 0, stream>>>(items, nU, nxt, accI, B);
            float* t = cur; cur = nxt; nxt = t;
        }
    }

    dot_pairs<<<(int)(((long)B * 16 + T - 1) / T), T, 0, stream>>>(accU, accI, gout, B);
}